// Round 4
// baseline (278.996 us; speedup 1.0000x reference)
//
#include <hip/hip_runtime.h>
#include <math.h>

#define B_    128
#define T_    24
#define NN    300
#define EE    9000
#define GG    (B_ * T_)
#define GRUH  12
#define OUTF  1200

#define NSPLIT    50     // node splits (300 = 50 * 6)
#define NODES_PER 6
#define GBLK      12     // 3072 / 256 graph-chunks
#define EWLD      3136   // padded ewT leading dim (floats): 12544 B = 49*256
#define XLD       3072   // xT leading dim

// ---------------------------------------------------------------------------
// Kernel 0: tiled transpose  src[3072][ncols] -> dst[ncols][ldd]
// Tile = 256 graphs x 32 cols. Write side: one 1KB contiguous float4 wave-
// store per output row (the HBM-bound direction). LDS [32][260]: write-phase
// b128 reads conflict-free, read-phase stores ~4-way (hidden under VMEM).
// ---------------------------------------------------------------------------
__global__ __launch_bounds__(256) void transpose_k(
    const float* __restrict__ src, float* __restrict__ dst, int ncols, int ldd)
{
    __shared__ float tile[32][260];
    const int g0 = blockIdx.x * 256;
    const int e0 = blockIdx.y * 32;
    const int tid = threadIdx.x;
    const int cols_here = min(32, ncols - e0);

    const int rr = tid >> 3;            // 0..31
    const int c4 = (tid & 7) << 2;      // 0,4,...,28
    if (c4 < cols_here) {
#pragma unroll
        for (int k = 0; k < 8; k++) {
            const int r = rr + (k << 5);   // 0..255
            const float4 v = *(const float4*)(src + (size_t)(g0 + r) * ncols + e0 + c4);
            tile[c4 + 0][r] = v.x; tile[c4 + 1][r] = v.y;
            tile[c4 + 2][r] = v.z; tile[c4 + 3][r] = v.w;
        }
    }
    __syncthreads();

    const int w  = tid >> 6;            // 0..3
    const int gc = (tid & 63) << 2;     // 0..252
#pragma unroll
    for (int k = 0; k < 8; k++) {
        const int er = w + (k << 2);    // 0..31
        if (er < cols_here) {
            float4 v;
            v.x = tile[er][gc + 0]; v.y = tile[er][gc + 1];
            v.z = tile[er][gc + 2]; v.w = tile[er][gc + 3];
            *(float4*)(dst + (size_t)(e0 + er) * ldd + g0 + gc) = v;
        }
    }
}

// ---------------------------------------------------------------------------
// Kernel 1: build CSR of edges grouped by dst (shared topology), + zero S.
// ---------------------------------------------------------------------------
__global__ __launch_bounds__(1024) void build_csr(
    const int* __restrict__ src, const int* __restrict__ dst,
    int* __restrict__ row_ptr, int2* __restrict__ edge2, float* __restrict__ S)
{
    __shared__ int cnt[512];
    __shared__ int bufA[512], bufB[512];
    __shared__ int offs[NN];
    const int tid = threadIdx.x;

    for (int i = tid; i < GG; i += 1024) S[i] = 0.f;   // zero accumulators

    for (int i = tid; i < 512; i += 1024) cnt[i] = 0;
    __syncthreads();
    for (int e = tid; e < EE; e += 1024) atomicAdd(&cnt[dst[e]], 1);
    __syncthreads();

    int* cur = bufA; int* nxt = bufB;
    if (tid < 512) cur[tid] = cnt[tid];
    __syncthreads();
    for (int d = 1; d < 512; d <<= 1) {
        if (tid < 512) nxt[tid] = cur[tid] + (tid >= d ? cur[tid - d] : 0);
        __syncthreads();
        int* t = cur; cur = nxt; nxt = t;
    }
    if (tid <= NN) row_ptr[tid] = (tid == 0) ? 0 : cur[tid - 1];
    if (tid < NN)  offs[tid]    = (tid == 0) ? 0 : cur[tid - 1];
    __syncthreads();

    for (int e = tid; e < EE; e += 1024) {
        int d = dst[e];
        int pos = atomicAdd(&offs[d], 1);
        edge2[pos] = make_int2(src[e], e);
    }
}

// ---------------------------------------------------------------------------
// Kernel 2: EdgeGAT + mean pool, lane = graph. Block = 256 threads = 4
// consecutive 64-graph waves, one 6-node split. Wave-uniform indices, fully
// coalesced 1KB data loads, zero gathers, zero divergence.
// ---------------------------------------------------------------------------
__global__ __launch_bounds__(256) void gat_pool_t(
    const float* __restrict__ ewT, const float* __restrict__ xT,
    const float* __restrict__ w_node, const float* __restrict__ w_edge,
    const float* __restrict__ attn_l, const float* __restrict__ attn_r,
    const float* __restrict__ attn_e,
    const int* __restrict__ row_ptr, const int2* __restrict__ edge2,
    float* __restrict__ S)
{
    const int tid   = threadIdx.x;
    const int chunk = blockIdx.x % GBLK;
    const int s     = blockIdx.x / GBLK;
    const int g     = chunk * 256 + tid;

    float cL = 0.f, cR = 0.f, cE = 0.f;
#pragma unroll
    for (int o = 0; o < 4; o++) {
        float wn = w_node[o];
        cL += wn * attn_l[o];
        cR += wn * attn_r[o];
        cE += w_edge[o] * attn_e[o];
    }

    float part = 0.f;
    const int n0 = s * NODES_PER;
    for (int n = n0; n < n0 + NODES_PER; n++) {
        const int beg = row_ptr[n];
        const int end = row_ptr[n + 1];
        const float base = cR * xT[(size_t)n * XLD + g];
        float den = 0.f, num = 0.f;
        int i = beg;
        for (; i + 4 <= end; i += 4) {
            const int2 ea = edge2[i];
            const int2 eb = edge2[i + 1];
            const int2 ec = edge2[i + 2];
            const int2 ed = edge2[i + 3];
            const float wa = ewT[(size_t)ea.y * EWLD + g];
            const float wb = ewT[(size_t)eb.y * EWLD + g];
            const float wc = ewT[(size_t)ec.y * EWLD + g];
            const float wd = ewT[(size_t)ed.y * EWLD + g];
            const float xa = xT[(size_t)ea.x * XLD + g];
            const float xb = xT[(size_t)eb.x * XLD + g];
            const float xc = xT[(size_t)ec.x * XLD + g];
            const float xd = xT[(size_t)ed.x * XLD + g];
            float v0 = fmaf(cL, xa, fmaf(cE, wa, base));
            float v1 = fmaf(cL, xb, fmaf(cE, wb, base));
            float v2 = fmaf(cL, xc, fmaf(cE, wc, base));
            float v3 = fmaf(cL, xd, fmaf(cE, wd, base));
            v0 = (v0 >= 0.f) ? v0 : 0.2f * v0;
            v1 = (v1 >= 0.f) ? v1 : 0.2f * v1;
            v2 = (v2 >= 0.f) ? v2 : 0.2f * v2;
            v3 = (v3 >= 0.f) ? v3 : 0.2f * v3;
            const float e0 = __expf(v0), e1 = __expf(v1);
            const float e2 = __expf(v2), e3 = __expf(v3);
            den += e0 + e1 + e2 + e3;
            num = fmaf(e0, xa, num);
            num = fmaf(e1, xb, num);
            num = fmaf(e2, xc, num);
            num = fmaf(e3, xd, num);
        }
        for (; i < end; i++) {
            const int2 ea = edge2[i];
            const float wa = ewT[(size_t)ea.y * EWLD + g];
            const float xa = xT[(size_t)ea.x * XLD + g];
            float v0 = fmaf(cL, xa, fmaf(cE, wa, base));
            v0 = (v0 >= 0.f) ? v0 : 0.2f * v0;
            const float e0 = __expf(v0);
            den += e0;
            num = fmaf(e0, xa, num);
        }
        if (end > beg) part += num / den;
    }
    unsafeAtomicAdd(&S[g], part);
}

// ---------------------------------------------------------------------------
// Kernel 3: fused GRU (wave 0, shuffle-only, 0 barriers in time loop) +
// FC 12->1200 across 256 threads with float4 weight rows.
// ---------------------------------------------------------------------------
__device__ __forceinline__ float sigmoidf_(float v) { return 1.0f / (1.0f + __expf(-v)); }

__global__ __launch_bounds__(256) void gru_fc(
    const float* __restrict__ S,
    const float* __restrict__ w_node, const float* __restrict__ gat_bias,
    const float* __restrict__ w_ih, const float* __restrict__ w_hh,
    const float* __restrict__ b_ih, const float* __restrict__ b_hh,
    const float* __restrict__ fc_w, const float* __restrict__ fc_b,
    float* __restrict__ out)
{
    __shared__ float hsh[GRUH];
    const int b = blockIdx.x;
    const int tid = threadIdx.x;

    if (tid < 64) {
        float wn[4], gb[4];
#pragma unroll
        for (int i = 0; i < 4; i++) {
            wn[i] = w_node[i] * (1.0f / (float)NN);
            gb[i] = gat_bias[i];
        }
        float wih[4] = {0.f, 0.f, 0.f, 0.f};
        float whh[12];
#pragma unroll
        for (int j = 0; j < 12; j++) whh[j] = 0.f;
        float bih = 0.f, bhh = 0.f;
        if (tid < 36) {
#pragma unroll
            for (int i = 0; i < 4; i++)  wih[i] = w_ih[tid * 4 + i];
#pragma unroll
            for (int j = 0; j < 12; j++) whh[j] = w_hh[tid * 12 + j];
            bih = b_ih[tid];
            bhh = b_hh[tid];
        }
        float srow = (tid < T_) ? S[(size_t)b * T_ + tid] : 0.f;
        float hreg = 0.f;
        const int l = tid % 12;
        for (int t = 0; t < T_; t++) {
            float Sg = __shfl(srow, t);
            float gi = bih, gh = bhh;
#pragma unroll
            for (int i = 0; i < 4; i++) gi += (Sg * wn[i] + gb[i]) * wih[i];
#pragma unroll
            for (int j = 0; j < 12; j++) gh += __shfl(hreg, j) * whh[j];
            float a   = gi + gh;
            float aiz = __shfl(a, 12 + l);
            float gin = __shfl(gi, 24 + l);
            float ghn = __shfl(gh, 24 + l);
            if (tid < 12) {
                float r = sigmoidf_(a);
                float z = sigmoidf_(aiz);
                float n = tanhf(gin + r * ghn);
                hreg = (1.f - z) * n + z * hreg;
            }
        }
        if (tid < GRUH) hsh[tid] = hreg;
    }
    __syncthreads();

    float h0 = hsh[0], h1 = hsh[1], h2 = hsh[2],  h3 = hsh[3];
    float h4 = hsh[4], h5 = hsh[5], h6 = hsh[6],  h7 = hsh[7];
    float h8 = hsh[8], h9 = hsh[9], hA = hsh[10], hB = hsh[11];
    for (int j = tid; j < OUTF; j += 256) {
        const float4* w4 = (const float4*)(fc_w + (size_t)j * GRUH);
        const float4 a = w4[0], c = w4[1], d = w4[2];
        float o = fc_b[j];
        o += h0 * a.x + h1 * a.y + h2 * a.z + h3 * a.w;
        o += h4 * c.x + h5 * c.y + h6 * c.z + h7 * c.w;
        o += h8 * d.x + h9 * d.y + hA * d.z + hB * d.w;
        out[(size_t)b * OUTF + j] = o;
    }
}

// ---------------------------------------------------------------------------
// Fallback path (small workspace): round-2 structure
// ---------------------------------------------------------------------------
__global__ __launch_bounds__(320) void gat_pool_csr(
    const float* __restrict__ x, const float* __restrict__ ew,
    const float* __restrict__ w_node, const float* __restrict__ w_edge,
    const float* __restrict__ attn_l, const float* __restrict__ attn_r,
    const float* __restrict__ attn_e,
    const int* __restrict__ row_ptr, const int2* __restrict__ edge2,
    float* __restrict__ S)
{
    __shared__ float xs[NN];
    __shared__ float red[5];
    const int g = blockIdx.x;
    const int tid = threadIdx.x;

    float cL = 0.f, cR = 0.f, cE = 0.f;
#pragma unroll
    for (int o = 0; o < 4; o++) {
        float wn = w_node[o];
        cL += wn * attn_l[o];
        cR += wn * attn_r[o];
        cE += w_edge[o] * attn_e[o];
    }
    const float* xrow = x + (size_t)g * NN;
    const float* erow = ew + (size_t)g * EE;
    for (int i = tid; i < NN; i += 320) xs[i] = xrow[i];
    __syncthreads();

    float acc = 0.f;
    if (tid < NN) {
        const int beg = row_ptr[tid];
        const int end = row_ptr[tid + 1];
        const float vb = cR * xs[tid];
        float den = 0.f, num = 0.f;
        for (int i = beg; i < end; i++) {
            const int2 e  = edge2[i];
            const float ev  = erow[e.y];
            const float xsv = xs[e.x];
            float v = fmaf(cL, xsv, fmaf(cE, ev, vb));
            v = (v >= 0.f) ? v : 0.2f * v;
            const float ex = __expf(v);
            den += ex;
            num = fmaf(ex, xsv, num);
        }
        if (end > beg) acc = num / den;
    }
    for (int off = 32; off > 0; off >>= 1) acc += __shfl_down(acc, off);
    if ((tid & 63) == 0) red[tid >> 6] = acc;
    __syncthreads();
    if (tid == 0) S[g] = red[0] + red[1] + red[2] + red[3] + red[4];
}

// ---------------------------------------------------------------------------
extern "C" void kernel_launch(void* const* d_in, const int* in_sizes, int n_in,
                              void* d_out, int out_size, void* d_ws, size_t ws_size,
                              hipStream_t stream)
{
    const float* x        = (const float*)d_in[0];
    const float* ew       = (const float*)d_in[1];
    const int*   src      = (const int*)d_in[2];
    const int*   dst      = (const int*)d_in[3];
    const float* w_node   = (const float*)d_in[4];
    const float* w_edge   = (const float*)d_in[5];
    const float* attn_l   = (const float*)d_in[6];
    const float* attn_r   = (const float*)d_in[7];
    const float* attn_e   = (const float*)d_in[8];
    const float* gat_bias = (const float*)d_in[9];
    const float* w_ih     = (const float*)d_in[10];
    const float* w_hh     = (const float*)d_in[11];
    const float* b_ih     = (const float*)d_in[12];
    const float* b_hh     = (const float*)d_in[13];
    const float* fc_w     = (const float*)d_in[14];
    const float* fc_b     = (const float*)d_in[15];
    float* out = (float*)d_out;

    char* ws = (char*)d_ws;
    const size_t ewT_b  = (size_t)EE * EWLD * 4;          // 112,896,000
    const size_t xT_b   = (size_t)NN * XLD * 4;           //   3,686,400
    const size_t needed = ewT_b + xT_b + GG * 4 + 1280 + (size_t)EE * 8;

    if (ws_size >= needed) {
        float* ewT     = (float*)ws;
        float* xT      = (float*)(ws + ewT_b);
        float* S       = (float*)(ws + ewT_b + xT_b);
        int*   row_ptr = (int*)(ws + ewT_b + xT_b + GG * 4);
        int2*  edge2   = (int2*)(ws + ewT_b + xT_b + GG * 4 + 1280);

        build_csr<<<1, 1024, 0, stream>>>(src, dst, row_ptr, edge2, S);
        transpose_k<<<dim3(GBLK, (EE + 31) / 32), 256, 0, stream>>>(ew, ewT, EE, EWLD);
        transpose_k<<<dim3(GBLK, (NN + 31) / 32), 256, 0, stream>>>(x, xT, NN, XLD);
        gat_pool_t<<<GBLK * NSPLIT, 256, 0, stream>>>(ewT, xT, w_node, w_edge,
                                                      attn_l, attn_r, attn_e,
                                                      row_ptr, edge2, S);
        gru_fc<<<B_, 256, 0, stream>>>(S, w_node, gat_bias, w_ih, w_hh,
                                       b_ih, b_hh, fc_w, fc_b, out);
    } else {
        // small-workspace fallback (round-2 structure)
        float* S       = (float*)ws;
        int*   row_ptr = (int*)(ws + GG * 4);
        int2*  edge2   = (int2*)(ws + GG * 4 + 1280);
        build_csr<<<1, 1024, 0, stream>>>(src, dst, row_ptr, edge2, S);
        gat_pool_csr<<<GG, 320, 0, stream>>>(x, ew, w_node, w_edge,
                                             attn_l, attn_r, attn_e,
                                             row_ptr, edge2, S);
        gru_fc<<<B_, 256, 0, stream>>>(S, w_node, gat_bias, w_ih, w_hh,
                                       b_ih, b_hh, fc_w, fc_b, out);
    }
}

// Round 5
// 278.101 us; speedup vs baseline: 1.0032x; 1.0032x over previous
//
#include <hip/hip_runtime.h>
#include <hip/hip_fp16.h>
#include <math.h>

#define B_    128
#define T_    24
#define NN    300
#define EE    9000
#define GG    (B_ * T_)
#define GRUH  12
#define OUTF  1200

#define NSPLIT    100    // node splits (300 = 100 * 3)
#define NODES_PER 3
#define GBLK      6      // 3072 / 512 graph-chunks (2 graphs per thread)
#define EWLDH     3136   // padded ewT leading dim in HALFs (6272 B = 49*128)
#define XLD       3072   // xT leading dim (floats)

// ---------------------------------------------------------------------------
// Kernel 1: build CSR of edges grouped by dst (shared topology), + zero S.
// Outputs: row_ptr[NN+1], csr_src[pos], csr_eid[pos], csr_pos[e] (inverse).
// ---------------------------------------------------------------------------
__global__ __launch_bounds__(1024) void build_csr(
    const int* __restrict__ src, const int* __restrict__ dst,
    int* __restrict__ row_ptr, int* __restrict__ csr_src,
    int* __restrict__ csr_eid, int* __restrict__ csr_pos,
    float* __restrict__ S)
{
    __shared__ int cnt[512];
    __shared__ int bufA[512], bufB[512];
    __shared__ int offs[NN];
    const int tid = threadIdx.x;

    for (int i = tid; i < GG; i += 1024) S[i] = 0.f;   // zero accumulators

    for (int i = tid; i < 512; i += 1024) cnt[i] = 0;
    __syncthreads();
    for (int e = tid; e < EE; e += 1024) atomicAdd(&cnt[dst[e]], 1);
    __syncthreads();

    int* cur = bufA; int* nxt = bufB;
    if (tid < 512) cur[tid] = cnt[tid];
    __syncthreads();
    for (int d = 1; d < 512; d <<= 1) {
        if (tid < 512) nxt[tid] = cur[tid] + (tid >= d ? cur[tid - d] : 0);
        __syncthreads();
        int* t = cur; cur = nxt; nxt = t;
    }
    if (tid <= NN) row_ptr[tid] = (tid == 0) ? 0 : cur[tid - 1];
    if (tid < NN)  offs[tid]    = (tid == 0) ? 0 : cur[tid - 1];
    __syncthreads();

    for (int e = tid; e < EE; e += 1024) {
        int d = dst[e];
        int pos = atomicAdd(&offs[d], 1);
        csr_src[pos] = src[e];
        csr_eid[pos] = e;
        csr_pos[e]   = pos;
    }
}

// ---------------------------------------------------------------------------
// Kernel 2a: fp32 transpose for x:  src[3072][ncols] -> dst[ncols][ldd]
// (tiny: 3.7 MB; round-4 structure)
// ---------------------------------------------------------------------------
__global__ __launch_bounds__(256) void transpose_f(
    const float* __restrict__ src, float* __restrict__ dst, int ncols, int ldd)
{
    __shared__ float tile[32][260];
    const int g0 = blockIdx.x * 256;
    const int e0 = blockIdx.y * 32;
    const int tid = threadIdx.x;
    const int cols_here = min(32, ncols - e0);

    const int rr = tid >> 3;
    const int c4 = (tid & 7) << 2;
    if (c4 < cols_here) {
#pragma unroll
        for (int k = 0; k < 8; k++) {
            const int r = rr + (k << 5);
            const float4 v = *(const float4*)(src + (size_t)(g0 + r) * ncols + e0 + c4);
            tile[c4 + 0][r] = v.x; tile[c4 + 1][r] = v.y;
            tile[c4 + 2][r] = v.z; tile[c4 + 3][r] = v.w;
        }
    }
    __syncthreads();

    const int w  = tid >> 6;
    const int gc = (tid & 63) << 2;
#pragma unroll
    for (int k = 0; k < 8; k++) {
        const int er = w + (k << 2);
        if (er < cols_here) {
            float4 v;
            v.x = tile[er][gc + 0]; v.y = tile[er][gc + 1];
            v.z = tile[er][gc + 2]; v.w = tile[er][gc + 3];
            *(float4*)(dst + (size_t)(e0 + er) * ldd + g0 + gc) = v;
        }
    }
}

// ---------------------------------------------------------------------------
// Kernel 2b: fp32 -> fp16 transpose for ew, with CSR-permuted output rows:
//   ewTC[csr_pos[e]][g] = (half)ew[g][e]
// Tile 128 graphs x 128 edges; LDS fp16 [128][134] = 34.3 KB (4 blocks/CU).
// Read pieces 512 B, write pieces 256 B (contiguous 128-graph fp16 runs).
// ---------------------------------------------------------------------------
__global__ __launch_bounds__(256) void transpose_h(
    const float* __restrict__ src, __half* __restrict__ dst,
    const int* __restrict__ csr_pos)
{
    __shared__ __half tileh[128][134];
    const int g0 = blockIdx.x * 128;
    const int e0 = blockIdx.y * 128;
    const int tid = threadIdx.x;
    const int cols_here = min(128, EE - e0);

    const int c4 = (tid & 31) << 2;        // edge col within tile
    if (c4 < cols_here) {
#pragma unroll
        for (int k = 0; k < 16; k++) {
            const int r = (tid >> 5) + (k << 3);   // graph row 0..127
            const float4 v = *(const float4*)(src + (size_t)(g0 + r) * EE + e0 + c4);
            __half2 h01, h23;
            h01.x = __float2half_rn(v.x); h01.y = __float2half_rn(v.y);
            h23.x = __float2half_rn(v.z); h23.y = __float2half_rn(v.w);
            *(__half2*)&tileh[r][c4 + 0] = h01;
            *(__half2*)&tileh[r][c4 + 2] = h23;
        }
    }
    __syncthreads();

    const int lane = tid & 63;
    const int g2 = lane << 1;
#pragma unroll
    for (int k = 0; k < 32; k++) {
        const int er = (tid >> 6) + (k << 2);      // edge row 0..127
        if (er < cols_here) {
            __half2 h;
            h.x = tileh[g2][er];
            h.y = tileh[g2 + 1][er];
            const int orow = csr_pos[e0 + er];
            *(__half2*)(dst + (size_t)orow * EWLDH + g0 + g2) = h;
        }
    }
}

// ---------------------------------------------------------------------------
// Kernel 3: EdgeGAT + mean pool, lane = 2 graphs (half2/float2 loads).
// Block = 256 threads = 512 graphs, one 3-node split. ewTC rows are in CSR
// order -> fully sequential streaming; csr_src gives the x gather row
// (wave-uniform scalar). Zero atomic contention in LDS; one global atomic
// per (graph, split).
// ---------------------------------------------------------------------------
__global__ __launch_bounds__(256) void gat_pool_t(
    const __half* __restrict__ ewTC, const float* __restrict__ xT,
    const float* __restrict__ w_node, const float* __restrict__ w_edge,
    const float* __restrict__ attn_l, const float* __restrict__ attn_r,
    const float* __restrict__ attn_e,
    const int* __restrict__ row_ptr, const int* __restrict__ csr_src,
    float* __restrict__ S)
{
    const int tid   = threadIdx.x;
    const int chunk = blockIdx.x % GBLK;
    const int s     = blockIdx.x / GBLK;
    const int gp    = chunk * 256 + tid;       // half2 / float2 index
    const int g2    = gp << 1;

    float cL = 0.f, cR = 0.f, cE = 0.f;
#pragma unroll
    for (int o = 0; o < 4; o++) {
        float wn = w_node[o];
        cL += wn * attn_l[o];
        cR += wn * attn_r[o];
        cE += w_edge[o] * attn_e[o];
    }

    const __half2* __restrict__ ew2 = (const __half2*)ewTC;   // pitch 1568
    const float2*  __restrict__ xT2 = (const float2*)xT;      // pitch 1536

    float p0 = 0.f, p1 = 0.f;
    const int n0 = s * NODES_PER;
    for (int n = n0; n < n0 + NODES_PER; n++) {
        const int beg = row_ptr[n];
        const int end = row_ptr[n + 1];
        const float2 xb = xT2[(size_t)n * (XLD / 2) + gp];
        const float base0 = cR * xb.x;
        const float base1 = cR * xb.y;
        float den0 = 0.f, num0 = 0.f, den1 = 0.f, num1 = 0.f;
        int i = beg;
        for (; i + 2 <= end; i += 2) {
            const int sa = csr_src[i];
            const int sb = csr_src[i + 1];
            const float2 wa = __half22float2(ew2[(size_t)i       * (EWLDH / 2) + gp]);
            const float2 wb = __half22float2(ew2[(size_t)(i + 1) * (EWLDH / 2) + gp]);
            const float2 xa = xT2[(size_t)sa * (XLD / 2) + gp];
            const float2 xb2 = xT2[(size_t)sb * (XLD / 2) + gp];
            float v0 = fmaf(cL, xa.x,  fmaf(cE, wa.x, base0));
            float v1 = fmaf(cL, xa.y,  fmaf(cE, wa.y, base1));
            float v2 = fmaf(cL, xb2.x, fmaf(cE, wb.x, base0));
            float v3 = fmaf(cL, xb2.y, fmaf(cE, wb.y, base1));
            v0 = (v0 >= 0.f) ? v0 : 0.2f * v0;
            v1 = (v1 >= 0.f) ? v1 : 0.2f * v1;
            v2 = (v2 >= 0.f) ? v2 : 0.2f * v2;
            v3 = (v3 >= 0.f) ? v3 : 0.2f * v3;
            const float e0v = __expf(v0), e1v = __expf(v1);
            const float e2v = __expf(v2), e3v = __expf(v3);
            den0 += e0v + e2v;
            den1 += e1v + e3v;
            num0 = fmaf(e0v, xa.x,  num0); num0 = fmaf(e2v, xb2.x, num0);
            num1 = fmaf(e1v, xa.y,  num1); num1 = fmaf(e3v, xb2.y, num1);
        }
        for (; i < end; i++) {
            const int sa = csr_src[i];
            const float2 wa = __half22float2(ew2[(size_t)i * (EWLDH / 2) + gp]);
            const float2 xa = xT2[(size_t)sa * (XLD / 2) + gp];
            float v0 = fmaf(cL, xa.x, fmaf(cE, wa.x, base0));
            float v1 = fmaf(cL, xa.y, fmaf(cE, wa.y, base1));
            v0 = (v0 >= 0.f) ? v0 : 0.2f * v0;
            v1 = (v1 >= 0.f) ? v1 : 0.2f * v1;
            const float e0v = __expf(v0), e1v = __expf(v1);
            den0 += e0v; den1 += e1v;
            num0 = fmaf(e0v, xa.x, num0);
            num1 = fmaf(e1v, xa.y, num1);
        }
        if (end > beg) { p0 += num0 / den0; p1 += num1 / den1; }
    }
    unsafeAtomicAdd(&S[g2],     p0);
    unsafeAtomicAdd(&S[g2 + 1], p1);
}

// ---------------------------------------------------------------------------
// Kernel 4: fused GRU (wave 0, shuffle-only) + FC 12->1200 across 256 threads.
// ---------------------------------------------------------------------------
__device__ __forceinline__ float sigmoidf_(float v) { return 1.0f / (1.0f + __expf(-v)); }

__global__ __launch_bounds__(256) void gru_fc(
    const float* __restrict__ S,
    const float* __restrict__ w_node, const float* __restrict__ gat_bias,
    const float* __restrict__ w_ih, const float* __restrict__ w_hh,
    const float* __restrict__ b_ih, const float* __restrict__ b_hh,
    const float* __restrict__ fc_w, const float* __restrict__ fc_b,
    float* __restrict__ out)
{
    __shared__ float hsh[GRUH];
    const int b = blockIdx.x;
    const int tid = threadIdx.x;

    if (tid < 64) {
        float wn[4], gb[4];
#pragma unroll
        for (int i = 0; i < 4; i++) {
            wn[i] = w_node[i] * (1.0f / (float)NN);
            gb[i] = gat_bias[i];
        }
        float wih[4] = {0.f, 0.f, 0.f, 0.f};
        float whh[12];
#pragma unroll
        for (int j = 0; j < 12; j++) whh[j] = 0.f;
        float bih = 0.f, bhh = 0.f;
        if (tid < 36) {
#pragma unroll
            for (int i = 0; i < 4; i++)  wih[i] = w_ih[tid * 4 + i];
#pragma unroll
            for (int j = 0; j < 12; j++) whh[j] = w_hh[tid * 12 + j];
            bih = b_ih[tid];
            bhh = b_hh[tid];
        }
        float srow = (tid < T_) ? S[(size_t)b * T_ + tid] : 0.f;
        float hreg = 0.f;
        const int l = tid % 12;
        for (int t = 0; t < T_; t++) {
            float Sg = __shfl(srow, t);
            float gi = bih, gh = bhh;
#pragma unroll
            for (int i = 0; i < 4; i++) gi += (Sg * wn[i] + gb[i]) * wih[i];
#pragma unroll
            for (int j = 0; j < 12; j++) gh += __shfl(hreg, j) * whh[j];
            float a   = gi + gh;
            float aiz = __shfl(a, 12 + l);
            float gin = __shfl(gi, 24 + l);
            float ghn = __shfl(gh, 24 + l);
            if (tid < 12) {
                float r = sigmoidf_(a);
                float z = sigmoidf_(aiz);
                float n = tanhf(gin + r * ghn);
                hreg = (1.f - z) * n + z * hreg;
            }
        }
        if (tid < GRUH) hsh[tid] = hreg;
    }
    __syncthreads();

    float h0 = hsh[0], h1 = hsh[1], h2 = hsh[2],  h3 = hsh[3];
    float h4 = hsh[4], h5 = hsh[5], h6 = hsh[6],  h7 = hsh[7];
    float h8 = hsh[8], h9 = hsh[9], hA = hsh[10], hB = hsh[11];
    for (int j = tid; j < OUTF; j += 256) {
        const float4* w4 = (const float4*)(fc_w + (size_t)j * GRUH);
        const float4 a = w4[0], c = w4[1], d = w4[2];
        float o = fc_b[j];
        o += h0 * a.x + h1 * a.y + h2 * a.z + h3 * a.w;
        o += h4 * c.x + h5 * c.y + h6 * c.z + h7 * c.w;
        o += h8 * d.x + h9 * d.y + hA * d.z + hB * d.w;
        out[(size_t)b * OUTF + j] = o;
    }
}

// ---------------------------------------------------------------------------
// Fallback path (small workspace): round-2 structure with split CSR arrays
// ---------------------------------------------------------------------------
__global__ __launch_bounds__(320) void gat_pool_csr(
    const float* __restrict__ x, const float* __restrict__ ew,
    const float* __restrict__ w_node, const float* __restrict__ w_edge,
    const float* __restrict__ attn_l, const float* __restrict__ attn_r,
    const float* __restrict__ attn_e,
    const int* __restrict__ row_ptr, const int* __restrict__ csr_src,
    const int* __restrict__ csr_eid,
    float* __restrict__ S)
{
    __shared__ float xs[NN];
    __shared__ float red[5];
    const int g = blockIdx.x;
    const int tid = threadIdx.x;

    float cL = 0.f, cR = 0.f, cE = 0.f;
#pragma unroll
    for (int o = 0; o < 4; o++) {
        float wn = w_node[o];
        cL += wn * attn_l[o];
        cR += wn * attn_r[o];
        cE += w_edge[o] * attn_e[o];
    }
    const float* xrow = x + (size_t)g * NN;
    const float* erow = ew + (size_t)g * EE;
    for (int i = tid; i < NN; i += 320) xs[i] = xrow[i];
    __syncthreads();

    float acc = 0.f;
    if (tid < NN) {
        const int beg = row_ptr[tid];
        const int end = row_ptr[tid + 1];
        const float vb = cR * xs[tid];
        float den = 0.f, num = 0.f;
        for (int i = beg; i < end; i++) {
            const float ev  = erow[csr_eid[i]];
            const float xsv = xs[csr_src[i]];
            float v = fmaf(cL, xsv, fmaf(cE, ev, vb));
            v = (v >= 0.f) ? v : 0.2f * v;
            const float ex = __expf(v);
            den += ex;
            num = fmaf(ex, xsv, num);
        }
        if (end > beg) acc = num / den;
    }
    for (int off = 32; off > 0; off >>= 1) acc += __shfl_down(acc, off);
    if ((tid & 63) == 0) red[tid >> 6] = acc;
    __syncthreads();
    if (tid == 0) S[g] = red[0] + red[1] + red[2] + red[3] + red[4];
}

// ---------------------------------------------------------------------------
extern "C" void kernel_launch(void* const* d_in, const int* in_sizes, int n_in,
                              void* d_out, int out_size, void* d_ws, size_t ws_size,
                              hipStream_t stream)
{
    const float* x        = (const float*)d_in[0];
    const float* ew       = (const float*)d_in[1];
    const int*   src      = (const int*)d_in[2];
    const int*   dst      = (const int*)d_in[3];
    const float* w_node   = (const float*)d_in[4];
    const float* w_edge   = (const float*)d_in[5];
    const float* attn_l   = (const float*)d_in[6];
    const float* attn_r   = (const float*)d_in[7];
    const float* attn_e   = (const float*)d_in[8];
    const float* gat_bias = (const float*)d_in[9];
    const float* w_ih     = (const float*)d_in[10];
    const float* w_hh     = (const float*)d_in[11];
    const float* b_ih     = (const float*)d_in[12];
    const float* b_hh     = (const float*)d_in[13];
    const float* fc_w     = (const float*)d_in[14];
    const float* fc_b     = (const float*)d_in[15];
    float* out = (float*)d_out;

    char* ws = (char*)d_ws;
    const size_t ewT_b = (size_t)EE * EWLDH * 2;   // 56,448,000
    const size_t xT_b  = (size_t)NN * XLD * 4;     //  3,686,400
    const size_t off_S    = ewT_b + xT_b;
    const size_t off_rp   = off_S + GG * 4;
    const size_t off_src  = off_rp + 304 * 4;
    const size_t off_eid  = off_src + EE * 4;
    const size_t off_pos  = off_eid + EE * 4;
    const size_t needed   = off_pos + EE * 4;

    if (ws_size >= needed) {
        __half* ewTC    = (__half*)ws;
        float*  xT      = (float*)(ws + ewT_b);
        float*  S       = (float*)(ws + off_S);
        int*    row_ptr = (int*)(ws + off_rp);
        int*    csr_src = (int*)(ws + off_src);
        int*    csr_eid = (int*)(ws + off_eid);
        int*    csr_pos = (int*)(ws + off_pos);

        build_csr<<<1, 1024, 0, stream>>>(src, dst, row_ptr, csr_src, csr_eid,
                                          csr_pos, S);
        transpose_f<<<dim3(12, 10), 256, 0, stream>>>(x, xT, NN, XLD);
        transpose_h<<<dim3(24, 71), 256, 0, stream>>>(ew, ewTC, csr_pos);
        gat_pool_t<<<GBLK * NSPLIT, 256, 0, stream>>>(ewTC, xT, w_node, w_edge,
                                                      attn_l, attn_r, attn_e,
                                                      row_ptr, csr_src, S);
        gru_fc<<<B_, 256, 0, stream>>>(S, w_node, gat_bias, w_ih, w_hh,
                                       b_ih, b_hh, fc_w, fc_b, out);
    } else {
        // small-workspace fallback (round-2 structure)
        float* S       = (float*)ws;
        int*   row_ptr = (int*)(ws + GG * 4);
        int*   csr_src = (int*)(ws + GG * 4 + 304 * 4);
        int*   csr_eid = (int*)(ws + GG * 4 + 304 * 4 + EE * 4);
        int*   csr_pos = (int*)(ws + GG * 4 + 304 * 4 + 2 * EE * 4);
        build_csr<<<1, 1024, 0, stream>>>(src, dst, row_ptr, csr_src, csr_eid,
                                          csr_pos, S);
        gat_pool_csr<<<GG, 320, 0, stream>>>(x, ew, w_node, w_edge,
                                             attn_l, attn_r, attn_e,
                                             row_ptr, csr_src, csr_eid, S);
        gru_fc<<<B_, 256, 0, stream>>>(S, w_node, gat_bias, w_ih, w_hh,
                                       b_ih, b_hh, fc_w, fc_b, out);
    }
}

// Round 6
// 254.826 us; speedup vs baseline: 1.0949x; 1.0913x over previous
//
#include <hip/hip_runtime.h>
#include <math.h>

#define B_    128
#define T_    24
#define NN    300
#define EE    9000
#define GG    (B_ * T_)
#define GRUH  12
#define OUTF  1200

// ---------------------------------------------------------------------------
// Kernel 1: build CSR of edges grouped by dst (topology shared by all 3072
// graphs). Per-wave privatized histograms kill same-address LDS-atomic
// serialization in both the count and scatter phases.
// Outputs: row_ptr[NN+1], csr_src[pos] (src node of CSR slot), csr_pos[e]
// (CSR slot of edge e). csr_eid not needed by the new gat_pool.
// ---------------------------------------------------------------------------
__global__ __launch_bounds__(1024) void build_csr(
    const int* __restrict__ src, const int* __restrict__ dst,
    int* __restrict__ row_ptr, int* __restrict__ csr_src, int* __restrict__ csr_pos)
{
    __shared__ int hist[16][512];          // 32 KB, wave w owns hist[w]
    __shared__ int cnt[512];
    __shared__ int bufA[512], bufB[512];
    const int tid  = threadIdx.x;
    const int wave = tid >> 6;

    for (int i = tid; i < 16 * 512; i += 1024) ((int*)hist)[i] = 0;
    __syncthreads();

    // count: intra-wave contention only (~avg 2-way)
    for (int e = tid; e < EE; e += 1024) atomicAdd(&hist[wave][dst[e]], 1);
    __syncthreads();

    // column-wise exclusive scan over the 16 waves; total -> cnt[n]
    if (tid < 512) {
        int s = 0;
#pragma unroll
        for (int w = 0; w < 16; w++) { int t = hist[w][tid]; hist[w][tid] = s; s += t; }
        cnt[tid] = s;
    }
    __syncthreads();

    // Hillis-Steele inclusive scan over 512 (padded) node counts
    int* cur = bufA; int* nxt = bufB;
    if (tid < 512) cur[tid] = cnt[tid];
    __syncthreads();
    for (int d = 1; d < 512; d <<= 1) {
        if (tid < 512) nxt[tid] = cur[tid] + (tid >= d ? cur[tid - d] : 0);
        __syncthreads();
        int* t = cur; cur = nxt; nxt = t;
    }
    if (tid <= NN) row_ptr[tid] = (tid == 0) ? 0 : cur[tid - 1];
    __syncthreads();

    // per-wave base = node_excl_prefix + wave_excl_prefix
    if (tid < 512) {
        const int base = (tid == 0) ? 0 : cur[tid - 1];
#pragma unroll
        for (int w = 0; w < 16; w++) hist[w][tid] += base;
    }
    __syncthreads();

    // scatter: same wave handles the same edges as in count phase
    for (int e = tid; e < EE; e += 1024) {
        const int d = dst[e];
        const int pos = atomicAdd(&hist[wave][d], 1);
        csr_src[pos] = src[e];
        csr_pos[e]   = pos;
    }
}

// ---------------------------------------------------------------------------
// Kernel 2: per-graph EdgeGAT + mean pool -> scalar S[g]. ONE pass over ew
// in native layout (the only compulsory HBM traffic).
//  pass 1 (edge-parallel, float4-coalesced): ex = exp(leakyrelu(v)) scattered
//         to evals[csr_pos[e]]  -> pass 2 reads are sequential.
//  pass 2 (node-per-lane, unrolled x4): den/num register accumulation.
// exp without max-shift (bounded logits; validated rounds 1-5).
// LDS 37.3 KB, 512 threads -> 4 blocks/CU = 32 waves/CU (100% occupancy).
// ---------------------------------------------------------------------------
__global__ __launch_bounds__(512) void gat_pool(
    const float* __restrict__ x, const float* __restrict__ ew,
    const int* __restrict__ src, const int* __restrict__ dst,
    const float* __restrict__ w_node, const float* __restrict__ w_edge,
    const float* __restrict__ attn_l, const float* __restrict__ attn_r,
    const float* __restrict__ attn_e,
    const int* __restrict__ row_ptr, const int* __restrict__ csr_src,
    const int* __restrict__ csr_pos,
    float* __restrict__ S)
{
    __shared__ float xs[NN];
    __shared__ float evals[EE];
    __shared__ float red[8];

    const int g = blockIdx.x;
    const int tid = threadIdx.x;

    float cL = 0.f, cR = 0.f, cE = 0.f;
#pragma unroll
    for (int o = 0; o < 4; o++) {
        float wn = w_node[o];
        cL += wn * attn_l[o];
        cR += wn * attn_r[o];
        cE += w_edge[o] * attn_e[o];
    }

    const float* xrow = x + (size_t)g * NN;
    const float* erow = ew + (size_t)g * EE;

    for (int i = tid; i < NN; i += 512) xs[i] = xrow[i];
    __syncthreads();

    // pass 1: coalesced float4 ew read, logits -> exp -> LDS scatter to CSR slot
    const float4* __restrict__ erow4 = (const float4*)erow;   // 36000 B row, 16B-aligned
    const int4*   __restrict__ src4  = (const int4*)src;
    const int4*   __restrict__ dst4  = (const int4*)dst;
    const int4*   __restrict__ pos4  = (const int4*)csr_pos;

#define PROC(sj, dj, pj, ev)                                        \
    {                                                               \
        float v = fmaf(cL, xs[(sj)], fmaf(cR, xs[(dj)], cE * (ev))); \
        v = (v >= 0.f) ? v : 0.2f * v;                              \
        evals[(pj)] = __expf(v);                                    \
    }

    for (int q = tid; q < EE / 4; q += 512) {   // 2250 quads
        const float4 e4 = erow4[q];
        const int4   s4 = src4[q];
        const int4   d4 = dst4[q];
        const int4   p4 = pos4[q];
        PROC(s4.x, d4.x, p4.x, e4.x);
        PROC(s4.y, d4.y, p4.y, e4.y);
        PROC(s4.z, d4.z, p4.z, e4.z);
        PROC(s4.w, d4.w, p4.w, e4.w);
    }
#undef PROC
    __syncthreads();

    // pass 2: lane = dst node; sequential evals + csr_src, xs gather; x4 MLP
    float acc = 0.f;
    if (tid < NN) {
        const int beg = row_ptr[tid];
        const int end = row_ptr[tid + 1];
        float den = 0.f, num = 0.f;
        int i = beg;
        for (; i + 4 <= end; i += 4) {
            const float e0 = evals[i],     e1 = evals[i + 1];
            const float e2 = evals[i + 2], e3 = evals[i + 3];
            const int   s0 = csr_src[i],     s1 = csr_src[i + 1];
            const int   s2 = csr_src[i + 2], s3 = csr_src[i + 3];
            const float x0 = xs[s0], x1 = xs[s1], x2 = xs[s2], x3 = xs[s3];
            den += (e0 + e1) + (e2 + e3);
            num = fmaf(e0, x0, num); num = fmaf(e1, x1, num);
            num = fmaf(e2, x2, num); num = fmaf(e3, x3, num);
        }
        for (; i < end; i++) {
            const float e0 = evals[i];
            den += e0;
            num = fmaf(e0, xs[csr_src[i]], num);
        }
        if (end > beg) acc = num / den;
    }

    // block reduce (8 waves)
    for (int off = 32; off > 0; off >>= 1) acc += __shfl_down(acc, off);
    if ((tid & 63) == 0) red[tid >> 6] = acc;
    __syncthreads();
    if (tid == 0) {
        float s = 0.f;
#pragma unroll
        for (int w = 0; w < 8; w++) s += red[w];
        S[g] = s;
    }
}

// ---------------------------------------------------------------------------
// Kernel 3: fused GRU (wave 0, shuffle-only, 0 barriers in time loop) +
// FC 12->1200 across 256 threads with float4 weight rows.
// pooled[b,t,o] = (S[g]/N) * w_node[o] + gat_bias[o]
// ---------------------------------------------------------------------------
__device__ __forceinline__ float sigmoidf_(float v) { return 1.0f / (1.0f + __expf(-v)); }

__global__ __launch_bounds__(256) void gru_fc(
    const float* __restrict__ S,
    const float* __restrict__ w_node, const float* __restrict__ gat_bias,
    const float* __restrict__ w_ih, const float* __restrict__ w_hh,
    const float* __restrict__ b_ih, const float* __restrict__ b_hh,
    const float* __restrict__ fc_w, const float* __restrict__ fc_b,
    float* __restrict__ out)
{
    __shared__ float hsh[GRUH];
    const int b = blockIdx.x;
    const int tid = threadIdx.x;

    if (tid < 64) {
        float wn[4], gb[4];
#pragma unroll
        for (int i = 0; i < 4; i++) {
            wn[i] = w_node[i] * (1.0f / (float)NN);
            gb[i] = gat_bias[i];
        }
        float wih[4] = {0.f, 0.f, 0.f, 0.f};
        float whh[12];
#pragma unroll
        for (int j = 0; j < 12; j++) whh[j] = 0.f;
        float bih = 0.f, bhh = 0.f;
        if (tid < 36) {
#pragma unroll
            for (int i = 0; i < 4; i++)  wih[i] = w_ih[tid * 4 + i];
#pragma unroll
            for (int j = 0; j < 12; j++) whh[j] = w_hh[tid * 12 + j];
            bih = b_ih[tid];
            bhh = b_hh[tid];
        }
        float srow = (tid < T_) ? S[(size_t)b * T_ + tid] : 0.f;
        float hreg = 0.f;
        const int l = tid % 12;
        for (int t = 0; t < T_; t++) {
            float Sg = __shfl(srow, t);
            float gi = bih, gh = bhh;
#pragma unroll
            for (int i = 0; i < 4; i++) gi += (Sg * wn[i] + gb[i]) * wih[i];
#pragma unroll
            for (int j = 0; j < 12; j++) gh += __shfl(hreg, j) * whh[j];
            float a   = gi + gh;
            float aiz = __shfl(a, 12 + l);
            float gin = __shfl(gi, 24 + l);
            float ghn = __shfl(gh, 24 + l);
            if (tid < 12) {
                float r = sigmoidf_(a);
                float z = sigmoidf_(aiz);
                float n = tanhf(gin + r * ghn);
                hreg = (1.f - z) * n + z * hreg;
            }
        }
        if (tid < GRUH) hsh[tid] = hreg;
    }
    __syncthreads();

    float h0 = hsh[0], h1 = hsh[1], h2 = hsh[2],  h3 = hsh[3];
    float h4 = hsh[4], h5 = hsh[5], h6 = hsh[6],  h7 = hsh[7];
    float h8 = hsh[8], h9 = hsh[9], hA = hsh[10], hB = hsh[11];
    for (int j = tid; j < OUTF; j += 256) {
        const float4* w4 = (const float4*)(fc_w + (size_t)j * GRUH);
        const float4 a = w4[0], c = w4[1], d = w4[2];
        float o = fc_b[j];
        o += h0 * a.x + h1 * a.y + h2 * a.z + h3 * a.w;
        o += h4 * c.x + h5 * c.y + h6 * c.z + h7 * c.w;
        o += h8 * d.x + h9 * d.y + hA * d.z + hB * d.w;
        out[(size_t)b * OUTF + j] = o;
    }
}

// ---------------------------------------------------------------------------
extern "C" void kernel_launch(void* const* d_in, const int* in_sizes, int n_in,
                              void* d_out, int out_size, void* d_ws, size_t ws_size,
                              hipStream_t stream)
{
    const float* x        = (const float*)d_in[0];
    const float* ew       = (const float*)d_in[1];
    const int*   src      = (const int*)d_in[2];
    const int*   dst      = (const int*)d_in[3];
    const float* w_node   = (const float*)d_in[4];
    const float* w_edge   = (const float*)d_in[5];
    const float* attn_l   = (const float*)d_in[6];
    const float* attn_r   = (const float*)d_in[7];
    const float* attn_e   = (const float*)d_in[8];
    const float* gat_bias = (const float*)d_in[9];
    const float* w_ih     = (const float*)d_in[10];
    const float* w_hh     = (const float*)d_in[11];
    const float* b_ih     = (const float*)d_in[12];
    const float* b_hh     = (const float*)d_in[13];
    const float* fc_w     = (const float*)d_in[14];
    const float* fc_b     = (const float*)d_in[15];
    float* out = (float*)d_out;

    // workspace: S[GG] f32 | row_ptr[304] | csr_src[EE] | csr_pos[EE]  (~86 KB)
    char* ws = (char*)d_ws;
    float* S       = (float*)ws;
    int*   row_ptr = (int*)(ws + GG * 4);
    int*   csr_src = row_ptr + 304;
    int*   csr_pos = csr_src + EE;

    build_csr<<<1, 1024, 0, stream>>>(src, dst, row_ptr, csr_src, csr_pos);
    gat_pool<<<GG, 512, 0, stream>>>(x, ew, src, dst, w_node, w_edge,
                                     attn_l, attn_r, attn_e,
                                     row_ptr, csr_src, csr_pos, S);
    gru_fc<<<B_, 256, 0, stream>>>(S, w_node, gat_bias, w_ih, w_hh,
                                   b_ih, b_hh, fc_w, fc_b, out);
}

// Round 7
// 227.442 us; speedup vs baseline: 1.2267x; 1.1204x over previous
//
#include <hip/hip_runtime.h>
#include <hip/hip_fp16.h>
#include <math.h>

#define B_    128
#define T_    24
#define NN    300
#define EE    9000
#define GG    (B_ * T_)
#define GRUH  12
#define OUTF  1200

// ---------------------------------------------------------------------------
// Kernel 1: build degree-SORTED CSR of edges grouped by dst (topology shared
// by all 3072 graphs). Nodes are ranked by descending degree (ties by id);
// CSR row r holds the edges of the r-th highest-degree node, so in gat_pool
// pass 2 the lanes of a wave have near-equal trip counts (max ~= avg).
// Per-wave privatized histograms avoid same-address LDS-atomic serialization.
// Outputs: row_ptr[NN+1] (rank space), csr_pos[e] (sorted CSR slot of edge e).
// csr_src is NOT needed: gat_pool packs ex*x_src into the eval slot.
// ---------------------------------------------------------------------------
__global__ __launch_bounds__(1024) void build_csr(
    const int* __restrict__ src, const int* __restrict__ dst,
    int* __restrict__ row_ptr, int* __restrict__ csr_pos)
{
    __shared__ int hist[16][512];          // 32 KB, wave w owns hist[w]
    __shared__ int cnt[512];
    __shared__ int rankv[512];
    __shared__ int bufA[512], bufB[512];
    const int tid  = threadIdx.x;
    const int wave = tid >> 6;
    (void)src;

    for (int i = tid; i < 16 * 512; i += 1024) ((int*)hist)[i] = 0;
    __syncthreads();

    // count: intra-wave contention only
    for (int e = tid; e < EE; e += 1024) atomicAdd(&hist[wave][dst[e]], 1);
    __syncthreads();

    // column-wise exclusive scan over the 16 waves; per-node total -> cnt[n]
    if (tid < 512) {
        int s = 0;
#pragma unroll
        for (int w = 0; w < 16; w++) { int t = hist[w][tid]; hist[w][tid] = s; s += t; }
        cnt[tid] = s;
    }
    __syncthreads();

    // rank nodes by descending degree (ties by id); O(N^2), LDS-broadcast reads
    if (tid < NN) {
        const int d = cnt[tid];
        int r = 0;
        for (int m = 0; m < NN; m++) {
            const int dm = cnt[m];
            r += (dm > d) || (dm == d && m < tid);
        }
        rankv[tid] = r;
    }
    if (tid < 512) bufA[tid] = 0;
    __syncthreads();
    if (tid < NN) bufA[rankv[tid]] = cnt[tid];   // degree in sorted order
    __syncthreads();

    // Hillis-Steele inclusive scan over sorted degrees (512 padded)
    int* cur = bufA; int* nxt = bufB;
    for (int d = 1; d < 512; d <<= 1) {
        if (tid < 512) nxt[tid] = cur[tid] + (tid >= d ? cur[tid - d] : 0);
        __syncthreads();
        int* t = cur; cur = nxt; nxt = t;
    }
    if (tid <= NN) row_ptr[tid] = (tid == 0) ? 0 : cur[tid - 1];

    // per-node scatter base = sorted exclusive prefix of its rank
    if (tid < 512) {
        int base = 0;
        if (tid < NN) { const int r = rankv[tid]; base = (r == 0) ? 0 : cur[r - 1]; }
#pragma unroll
        for (int w = 0; w < 16; w++) hist[w][tid] += base;
    }
    __syncthreads();

    // scatter: slot for each edge in sorted-CSR space
    for (int e = tid; e < EE; e += 1024) {
        const int d = dst[e];
        const int pos = atomicAdd(&hist[wave][d], 1);
        csr_pos[e] = pos;
    }
}

// ---------------------------------------------------------------------------
// Kernel 2: per-graph EdgeGAT + mean pool -> scalar S[g]. ONE pass over ew
// in native layout (the only compulsory HBM traffic).
//  pass 1 (edge-parallel, float4-coalesced): ex = exp(leakyrelu(v));
//         pack half2(ex, ex*x_src) -> 4B scatter to evals[csr_pos[e]].
//  pass 2 (rank-per-lane, degree-balanced): SEQUENTIAL b64 eval reads only —
//         no LDS gathers, no global index stream. den += ex; num += ex*x.
// exp without max-shift (bounded logits; validated rounds 1-6); fminf(v,11)
// guards fp16 range. LDS 37.3 KB, 512 threads -> 4 blocks/CU.
// ---------------------------------------------------------------------------
__global__ __launch_bounds__(512) void gat_pool(
    const float* __restrict__ x, const float* __restrict__ ew,
    const int* __restrict__ src, const int* __restrict__ dst,
    const float* __restrict__ w_node, const float* __restrict__ w_edge,
    const float* __restrict__ attn_l, const float* __restrict__ attn_r,
    const float* __restrict__ attn_e,
    const int* __restrict__ row_ptr, const int* __restrict__ csr_pos,
    float* __restrict__ S)
{
    __shared__ float xs[NN];
    __shared__ __align__(16) unsigned int evals[EE];   // half2(ex, ex*x_src)
    __shared__ float red[8];

    const int g = blockIdx.x;
    const int tid = threadIdx.x;

    float cL = 0.f, cR = 0.f, cE = 0.f;
#pragma unroll
    for (int o = 0; o < 4; o++) {
        float wn = w_node[o];
        cL += wn * attn_l[o];
        cR += wn * attn_r[o];
        cE += w_edge[o] * attn_e[o];
    }

    const float* xrow = x + (size_t)g * NN;
    const float* erow = ew + (size_t)g * EE;

    for (int i = tid; i < NN; i += 512) xs[i] = xrow[i];
    __syncthreads();

    // pass 1: coalesced float4 ew read -> packed exp scatter to sorted slot
    const float4* __restrict__ erow4 = (const float4*)erow;   // 36000 B row
    const int4*   __restrict__ src4  = (const int4*)src;
    const int4*   __restrict__ dst4  = (const int4*)dst;
    const int4*   __restrict__ pos4  = (const int4*)csr_pos;

#define PROC(sj, dj, pj, ev)                                         \
    {                                                                \
        const float xsv = xs[(sj)];                                  \
        float v = fmaf(cL, xsv, fmaf(cR, xs[(dj)], cE * (ev)));      \
        v = (v >= 0.f) ? v : 0.2f * v;                               \
        v = fminf(v, 11.0f);                                         \
        const float ex = __expf(v);                                  \
        union { __half2 h2; unsigned int u; } c;                     \
        c.h2 = __halves2half2(__float2half_rn(ex),                   \
                              __float2half_rn(ex * xsv));            \
        evals[(pj)] = c.u;                                           \
    }

    for (int q = tid; q < EE / 4; q += 512) {   // 2250 quads
        const float4 e4 = erow4[q];
        const int4   s4 = src4[q];
        const int4   d4 = dst4[q];
        const int4   p4 = pos4[q];
        PROC(s4.x, d4.x, p4.x, e4.x);
        PROC(s4.y, d4.y, p4.y, e4.y);
        PROC(s4.z, d4.z, p4.z, e4.z);
        PROC(s4.w, d4.w, p4.w, e4.w);
    }
#undef PROC
    __syncthreads();

    // pass 2: lane = degree rank; sequential b64 reads, register accumulation
    float acc = 0.f;
    if (tid < NN) {
        const int beg = row_ptr[tid];
        const int end = row_ptr[tid + 1];
        float den = 0.f, num = 0.f;
        int i = beg;
        if ((i & 1) && i < end) {
            union { unsigned int u; __half2 h2; } c; c.u = evals[i++];
            const float2 f = __half22float2(c.h2);
            den += f.x; num += f.y;
        }
        for (; i + 4 <= end; i += 4) {
            const uint2 a = *(const uint2*)(evals + i);
            const uint2 b = *(const uint2*)(evals + i + 2);
            union { unsigned int u; __half2 h2; } c0, c1, c2, c3;
            c0.u = a.x; c1.u = a.y; c2.u = b.x; c3.u = b.y;
            const float2 f0 = __half22float2(c0.h2);
            const float2 f1 = __half22float2(c1.h2);
            const float2 f2 = __half22float2(c2.h2);
            const float2 f3 = __half22float2(c3.h2);
            den += (f0.x + f1.x) + (f2.x + f3.x);
            num += (f0.y + f1.y) + (f2.y + f3.y);
        }
        for (; i < end; i++) {
            union { unsigned int u; __half2 h2; } c; c.u = evals[i];
            const float2 f = __half22float2(c.h2);
            den += f.x; num += f.y;
        }
        if (end > beg) acc = num / den;
    }

    // block reduce (8 waves)
    for (int off = 32; off > 0; off >>= 1) acc += __shfl_down(acc, off);
    if ((tid & 63) == 0) red[tid >> 6] = acc;
    __syncthreads();
    if (tid == 0) {
        float s = 0.f;
#pragma unroll
        for (int w = 0; w < 8; w++) s += red[w];
        S[g] = s;
    }
}

// ---------------------------------------------------------------------------
// Kernel 3: fused GRU (wave 0, shuffle-only, 0 barriers in time loop) +
// FC 12->1200 across 256 threads with float4 weight rows.
// pooled[b,t,o] = (S[g]/N) * w_node[o] + gat_bias[o]
// ---------------------------------------------------------------------------
__device__ __forceinline__ float sigmoidf_(float v) { return 1.0f / (1.0f + __expf(-v)); }

__global__ __launch_bounds__(256) void gru_fc(
    const float* __restrict__ S,
    const float* __restrict__ w_node, const float* __restrict__ gat_bias,
    const float* __restrict__ w_ih, const float* __restrict__ w_hh,
    const float* __restrict__ b_ih, const float* __restrict__ b_hh,
    const float* __restrict__ fc_w, const float* __restrict__ fc_b,
    float* __restrict__ out)
{
    __shared__ float hsh[GRUH];
    const int b = blockIdx.x;
    const int tid = threadIdx.x;

    if (tid < 64) {
        float wn[4], gb[4];
#pragma unroll
        for (int i = 0; i < 4; i++) {
            wn[i] = w_node[i] * (1.0f / (float)NN);
            gb[i] = gat_bias[i];
        }
        float wih[4] = {0.f, 0.f, 0.f, 0.f};
        float whh[12];
#pragma unroll
        for (int j = 0; j < 12; j++) whh[j] = 0.f;
        float bih = 0.f, bhh = 0.f;
        if (tid < 36) {
#pragma unroll
            for (int i = 0; i < 4; i++)  wih[i] = w_ih[tid * 4 + i];
#pragma unroll
            for (int j = 0; j < 12; j++) whh[j] = w_hh[tid * 12 + j];
            bih = b_ih[tid];
            bhh = b_hh[tid];
        }
        float srow = (tid < T_) ? S[(size_t)b * T_ + tid] : 0.f;
        float hreg = 0.f;
        const int l = tid % 12;
        for (int t = 0; t < T_; t++) {
            float Sg = __shfl(srow, t);
            float gi = bih, gh = bhh;
#pragma unroll
            for (int i = 0; i < 4; i++) gi += (Sg * wn[i] + gb[i]) * wih[i];
#pragma unroll
            for (int j = 0; j < 12; j++) gh += __shfl(hreg, j) * whh[j];
            float a   = gi + gh;
            float aiz = __shfl(a, 12 + l);
            float gin = __shfl(gi, 24 + l);
            float ghn = __shfl(gh, 24 + l);
            if (tid < 12) {
                float r = sigmoidf_(a);
                float z = sigmoidf_(aiz);
                float n = tanhf(gin + r * ghn);
                hreg = (1.f - z) * n + z * hreg;
            }
        }
        if (tid < GRUH) hsh[tid] = hreg;
    }
    __syncthreads();

    float h0 = hsh[0], h1 = hsh[1], h2 = hsh[2],  h3 = hsh[3];
    float h4 = hsh[4], h5 = hsh[5], h6 = hsh[6],  h7 = hsh[7];
    float h8 = hsh[8], h9 = hsh[9], hA = hsh[10], hB = hsh[11];
    for (int j = tid; j < OUTF; j += 256) {
        const float4* w4 = (const float4*)(fc_w + (size_t)j * GRUH);
        const float4 a = w4[0], c = w4[1], d = w4[2];
        float o = fc_b[j];
        o += h0 * a.x + h1 * a.y + h2 * a.z + h3 * a.w;
        o += h4 * c.x + h5 * c.y + h6 * c.z + h7 * c.w;
        o += h8 * d.x + h9 * d.y + hA * d.z + hB * d.w;
        out[(size_t)b * OUTF + j] = o;
    }
}

// ---------------------------------------------------------------------------
extern "C" void kernel_launch(void* const* d_in, const int* in_sizes, int n_in,
                              void* d_out, int out_size, void* d_ws, size_t ws_size,
                              hipStream_t stream)
{
    const float* x        = (const float*)d_in[0];
    const float* ew       = (const float*)d_in[1];
    const int*   src      = (const int*)d_in[2];
    const int*   dst      = (const int*)d_in[3];
    const float* w_node   = (const float*)d_in[4];
    const float* w_edge   = (const float*)d_in[5];
    const float* attn_l   = (const float*)d_in[6];
    const float* attn_r   = (const float*)d_in[7];
    const float* attn_e   = (const float*)d_in[8];
    const float* gat_bias = (const float*)d_in[9];
    const float* w_ih     = (const float*)d_in[10];
    const float* w_hh     = (const float*)d_in[11];
    const float* b_ih     = (const float*)d_in[12];
    const float* b_hh     = (const float*)d_in[13];
    const float* fc_w     = (const float*)d_in[14];
    const float* fc_b     = (const float*)d_in[15];
    float* out = (float*)d_out;

    // workspace: S[GG] f32 | row_ptr[304] | csr_pos[EE]  (~50 KB)
    char* ws = (char*)d_ws;
    float* S       = (float*)ws;
    int*   row_ptr = (int*)(ws + GG * 4);
    int*   csr_pos = row_ptr + 304;

    build_csr<<<1, 1024, 0, stream>>>(src, dst, row_ptr, csr_pos);
    gat_pool<<<GG, 512, 0, stream>>>(x, ew, src, dst, w_node, w_edge,
                                     attn_l, attn_r, attn_e,
                                     row_ptr, csr_pos, S);
    gru_fc<<<B_, 256, 0, stream>>>(S, w_node, gat_bias, w_ih, w_hh,
                                   b_ih, b_hh, fc_w, fc_b, out);
}

// Round 8
// 224.237 us; speedup vs baseline: 1.2442x; 1.0143x over previous
//
#include <hip/hip_runtime.h>
#include <hip/hip_fp16.h>
#include <math.h>

#define B_    128
#define T_    24
#define NN    300
#define EE    9000
#define GG    (B_ * T_)
#define GRUH  12
#define OUTF  1200
#define NSPL  212      // rows 0..211 (largest after degree sort) get a helper lane

// ---------------------------------------------------------------------------
// Kernel 1: build degree-SORTED CSR of edges grouped by dst (topology shared
// by all 3072 graphs). CSR row r = edges of the r-th highest-degree node.
// Outputs: row_ptr[NN+1] (rank space), csr_pos[e] (sorted CSR slot of edge e).
// ---------------------------------------------------------------------------
__global__ __launch_bounds__(1024) void build_csr(
    const int* __restrict__ src, const int* __restrict__ dst,
    int* __restrict__ row_ptr, int* __restrict__ csr_pos)
{
    __shared__ int hist[16][512];          // 32 KB, wave w owns hist[w]
    __shared__ int cnt[512];
    __shared__ int rankv[512];
    __shared__ int bufA[512], bufB[512];
    const int tid  = threadIdx.x;
    const int wave = tid >> 6;
    (void)src;

    for (int i = tid; i < 16 * 512; i += 1024) ((int*)hist)[i] = 0;
    __syncthreads();

    for (int e = tid; e < EE; e += 1024) atomicAdd(&hist[wave][dst[e]], 1);
    __syncthreads();

    if (tid < 512) {
        int s = 0;
#pragma unroll
        for (int w = 0; w < 16; w++) { int t = hist[w][tid]; hist[w][tid] = s; s += t; }
        cnt[tid] = s;
    }
    __syncthreads();

    // rank nodes by descending degree (ties by id)
    if (tid < NN) {
        const int d = cnt[tid];
        int r = 0;
        for (int m = 0; m < NN; m++) {
            const int dm = cnt[m];
            r += (dm > d) || (dm == d && m < tid);
        }
        rankv[tid] = r;
    }
    if (tid < 512) bufA[tid] = 0;
    __syncthreads();
    if (tid < NN) bufA[rankv[tid]] = cnt[tid];
    __syncthreads();

    int* cur = bufA; int* nxt = bufB;
    for (int d = 1; d < 512; d <<= 1) {
        if (tid < 512) nxt[tid] = cur[tid] + (tid >= d ? cur[tid - d] : 0);
        __syncthreads();
        int* t = cur; cur = nxt; nxt = t;
    }
    if (tid <= NN) row_ptr[tid] = (tid == 0) ? 0 : cur[tid - 1];

    if (tid < 512) {
        int base = 0;
        if (tid < NN) { const int r = rankv[tid]; base = (r == 0) ? 0 : cur[r - 1]; }
#pragma unroll
        for (int w = 0; w < 16; w++) hist[w][tid] += base;
    }
    __syncthreads();

    for (int e = tid; e < EE; e += 1024) {
        const int d = dst[e];
        const int pos = atomicAdd(&hist[wave][d], 1);
        csr_pos[e] = pos;
    }
}

// ---------------------------------------------------------------------------
// Kernel 2: per-graph EdgeGAT + mean pool -> scalar S[g]. ONE pass over ew.
//  pass 1: statically flattened (2 pair-iterations + tail) so both quads'
//          index/data loads issue up front -> real MLP. Packs
//          half2(ex, ex*x_src) -> 4B scatter to evals[csr_pos[e]].
//  pass 2: degree-balanced + SPLIT: lanes 300-511 help rows 0-211 (the
//          largest) by taking the second half of the row. Critical path
//          ~ max_degree/2 sequential b64 reads.
// ---------------------------------------------------------------------------
__global__ __launch_bounds__(512) void gat_pool(
    const float* __restrict__ x, const float* __restrict__ ew,
    const int* __restrict__ src, const int* __restrict__ dst,
    const float* __restrict__ w_node, const float* __restrict__ w_edge,
    const float* __restrict__ attn_l, const float* __restrict__ attn_r,
    const float* __restrict__ attn_e,
    const int* __restrict__ row_ptr, const int* __restrict__ csr_pos,
    float* __restrict__ S)
{
    __shared__ float xs[NN];
    __shared__ __align__(16) unsigned int evals[EE];   // half2(ex, ex*x_src)
    __shared__ float2 part[NSPL];
    __shared__ float red[8];

    const int g = blockIdx.x;
    const int tid = threadIdx.x;

    float cL = 0.f, cR = 0.f, cE = 0.f;
#pragma unroll
    for (int o = 0; o < 4; o++) {
        float wn = w_node[o];
        cL += wn * attn_l[o];
        cR += wn * attn_r[o];
        cE += w_edge[o] * attn_e[o];
    }

    const float* xrow = x + (size_t)g * NN;
    const float* erow = ew + (size_t)g * EE;

    if (tid < NN / 4) ((float4*)xs)[tid] = ((const float4*)xrow)[tid];   // 75 float4
    __syncthreads();

    const float4* __restrict__ erow4 = (const float4*)erow;
    const int4*   __restrict__ src4  = (const int4*)src;
    const int4*   __restrict__ dst4  = (const int4*)dst;
    const int4*   __restrict__ pos4  = (const int4*)csr_pos;

#define PROCQ(e4, s4, d4, p4)                                        \
    {                                                                \
        const float xa = xs[s4.x], xb = xs[s4.y];                    \
        const float xc = xs[s4.z], xd = xs[s4.w];                    \
        const float ya = xs[d4.x], yb = xs[d4.y];                    \
        const float yc = xs[d4.z], yd = xs[d4.w];                    \
        float v0 = fmaf(cL, xa, fmaf(cR, ya, cE * e4.x));            \
        float v1 = fmaf(cL, xb, fmaf(cR, yb, cE * e4.y));            \
        float v2 = fmaf(cL, xc, fmaf(cR, yc, cE * e4.z));            \
        float v3 = fmaf(cL, xd, fmaf(cR, yd, cE * e4.w));            \
        v0 = fminf((v0 >= 0.f) ? v0 : 0.2f * v0, 11.0f);             \
        v1 = fminf((v1 >= 0.f) ? v1 : 0.2f * v1, 11.0f);             \
        v2 = fminf((v2 >= 0.f) ? v2 : 0.2f * v2, 11.0f);             \
        v3 = fminf((v3 >= 0.f) ? v3 : 0.2f * v3, 11.0f);             \
        const float ex0 = __expf(v0), ex1 = __expf(v1);              \
        const float ex2 = __expf(v2), ex3 = __expf(v3);              \
        union { __half2 h2; unsigned int u; } c0, c1, c2, c3;        \
        c0.h2 = __halves2half2(__float2half_rn(ex0), __float2half_rn(ex0 * xa)); \
        c1.h2 = __halves2half2(__float2half_rn(ex1), __float2half_rn(ex1 * xb)); \
        c2.h2 = __halves2half2(__float2half_rn(ex2), __float2half_rn(ex2 * xc)); \
        c3.h2 = __halves2half2(__float2half_rn(ex3), __float2half_rn(ex3 * xd)); \
        evals[p4.x] = c0.u; evals[p4.y] = c1.u;                      \
        evals[p4.z] = c2.u; evals[p4.w] = c3.u;                      \
    }

    // 2250 quads = 4*512 + 202, statically flattened for MLP
    {
        const int qa = tid, qb = tid + 512;
        const float4 eA = erow4[qa]; const int4 sA = src4[qa];
        const int4   dA = dst4[qa];  const int4 pA = pos4[qa];
        const float4 eB = erow4[qb]; const int4 sB = src4[qb];
        const int4   dB = dst4[qb];  const int4 pB = pos4[qb];
        PROCQ(eA, sA, dA, pA);
        PROCQ(eB, sB, dB, pB);
    }
    {
        const int qa = tid + 1024, qb = tid + 1536;
        const float4 eA = erow4[qa]; const int4 sA = src4[qa];
        const int4   dA = dst4[qa];  const int4 pA = pos4[qa];
        const float4 eB = erow4[qb]; const int4 sB = src4[qb];
        const int4   dB = dst4[qb];  const int4 pB = pos4[qb];
        PROCQ(eA, sA, dA, pA);
        PROCQ(eB, sB, dB, pB);
    }
    if (tid < 2250 - 2048) {
        const int qa = tid + 2048;
        const float4 eA = erow4[qa]; const int4 sA = src4[qa];
        const int4   dA = dst4[qa];  const int4 pA = pos4[qa];
        PROCQ(eA, sA, dA, pA);
    }
#undef PROCQ
    __syncthreads();

    // pass 2: primary lanes 0-299 (row = tid); helper lanes 300-511 take the
    // second half of rows 0-211. Sequential b64 reads, register accumulation.
    const bool isHelper = (tid >= NN);
    const int  row      = isHelper ? (tid - NN) : tid;
    float den = 0.f, num = 0.f;
    int beg = 0, end = 0;
    if (tid < NN + NSPL) {
        beg = row_ptr[row];
        end = row_ptr[row + 1];
        const bool split = (row < NSPL);
        int lo = beg, hi = end;
        if (split) {
            const int mid = (beg + end) >> 1;
            lo = isHelper ? mid : beg;
            hi = isHelper ? end : mid;
        }
        int i = lo;
        if ((i & 1) && i < hi) {
            union { unsigned int u; __half2 h2; } c; c.u = evals[i++];
            const float2 f = __half22float2(c.h2);
            den += f.x; num += f.y;
        }
        for (; i + 4 <= hi; i += 4) {
            const uint2 a = *(const uint2*)(evals + i);
            const uint2 b = *(const uint2*)(evals + i + 2);
            union { unsigned int u; __half2 h2; } c0, c1, c2, c3;
            c0.u = a.x; c1.u = a.y; c2.u = b.x; c3.u = b.y;
            const float2 f0 = __half22float2(c0.h2);
            const float2 f1 = __half22float2(c1.h2);
            const float2 f2 = __half22float2(c2.h2);
            const float2 f3 = __half22float2(c3.h2);
            den += (f0.x + f1.x) + (f2.x + f3.x);
            num += (f0.y + f1.y) + (f2.y + f3.y);
        }
        for (; i < hi; i++) {
            union { unsigned int u; __half2 h2; } c; c.u = evals[i];
            const float2 f = __half22float2(c.h2);
            den += f.x; num += f.y;
        }
        if (isHelper) part[row] = make_float2(den, num);
    }
    __syncthreads();

    float acc = 0.f;
    if (tid < NN) {
        if (row < NSPL) { den += part[row].x; num += part[row].y; }
        if (end > beg) acc = num / den;
    }

    // block reduce (8 waves)
    for (int off = 32; off > 0; off >>= 1) acc += __shfl_down(acc, off);
    if ((tid & 63) == 0) red[tid >> 6] = acc;
    __syncthreads();
    if (tid == 0) {
        float s = 0.f;
#pragma unroll
        for (int w = 0; w < 8; w++) s += red[w];
        S[g] = s;
    }
}

// ---------------------------------------------------------------------------
// Kernel 3: fused GRU (wave 0, shuffle-only, 0 barriers in time loop) +
// FC 12->1200 across 256 threads with float4 weight rows.
// pooled[b,t,o] = (S[g]/N) * w_node[o] + gat_bias[o]
// ---------------------------------------------------------------------------
__device__ __forceinline__ float sigmoidf_(float v) { return 1.0f / (1.0f + __expf(-v)); }

__global__ __launch_bounds__(256) void gru_fc(
    const float* __restrict__ S,
    const float* __restrict__ w_node, const float* __restrict__ gat_bias,
    const float* __restrict__ w_ih, const float* __restrict__ w_hh,
    const float* __restrict__ b_ih, const float* __restrict__ b_hh,
    const float* __restrict__ fc_w, const float* __restrict__ fc_b,
    float* __restrict__ out)
{
    __shared__ float hsh[GRUH];
    const int b = blockIdx.x;
    const int tid = threadIdx.x;

    if (tid < 64) {
        float wn[4], gb[4];
#pragma unroll
        for (int i = 0; i < 4; i++) {
            wn[i] = w_node[i] * (1.0f / (float)NN);
            gb[i] = gat_bias[i];
        }
        float wih[4] = {0.f, 0.f, 0.f, 0.f};
        float whh[12];
#pragma unroll
        for (int j = 0; j < 12; j++) whh[j] = 0.f;
        float bih = 0.f, bhh = 0.f;
        if (tid < 36) {
#pragma unroll
            for (int i = 0; i < 4; i++)  wih[i] = w_ih[tid * 4 + i];
#pragma unroll
            for (int j = 0; j < 12; j++) whh[j] = w_hh[tid * 12 + j];
            bih = b_ih[tid];
            bhh = b_hh[tid];
        }
        float srow = (tid < T_) ? S[(size_t)b * T_ + tid] : 0.f;
        float hreg = 0.f;
        const int l = tid % 12;
        for (int t = 0; t < T_; t++) {
            float Sg = __shfl(srow, t);
            float gi = bih, gh = bhh;
#pragma unroll
            for (int i = 0; i < 4; i++) gi += (Sg * wn[i] + gb[i]) * wih[i];
#pragma unroll
            for (int j = 0; j < 12; j++) gh += __shfl(hreg, j) * whh[j];
            float a   = gi + gh;
            float aiz = __shfl(a, 12 + l);
            float gin = __shfl(gi, 24 + l);
            float ghn = __shfl(gh, 24 + l);
            if (tid < 12) {
                float r = sigmoidf_(a);
                float z = sigmoidf_(aiz);
                float n = tanhf(gin + r * ghn);
                hreg = (1.f - z) * n + z * hreg;
            }
        }
        if (tid < GRUH) hsh[tid] = hreg;
    }
    __syncthreads();

    float h0 = hsh[0], h1 = hsh[1], h2 = hsh[2],  h3 = hsh[3];
    float h4 = hsh[4], h5 = hsh[5], h6 = hsh[6],  h7 = hsh[7];
    float h8 = hsh[8], h9 = hsh[9], hA = hsh[10], hB = hsh[11];
    for (int j = tid; j < OUTF; j += 256) {
        const float4* w4 = (const float4*)(fc_w + (size_t)j * GRUH);
        const float4 a = w4[0], c = w4[1], d = w4[2];
        float o = fc_b[j];
        o += h0 * a.x + h1 * a.y + h2 * a.z + h3 * a.w;
        o += h4 * c.x + h5 * c.y + h6 * c.z + h7 * c.w;
        o += h8 * d.x + h9 * d.y + hA * d.z + hB * d.w;
        out[(size_t)b * OUTF + j] = o;
    }
}

// ---------------------------------------------------------------------------
extern "C" void kernel_launch(void* const* d_in, const int* in_sizes, int n_in,
                              void* d_out, int out_size, void* d_ws, size_t ws_size,
                              hipStream_t stream)
{
    const float* x        = (const float*)d_in[0];
    const float* ew       = (const float*)d_in[1];
    const int*   src      = (const int*)d_in[2];
    const int*   dst      = (const int*)d_in[3];
    const float* w_node   = (const float*)d_in[4];
    const float* w_edge   = (const float*)d_in[5];
    const float* attn_l   = (const float*)d_in[6];
    const float* attn_r   = (const float*)d_in[7];
    const float* attn_e   = (const float*)d_in[8];
    const float* gat_bias = (const float*)d_in[9];
    const float* w_ih     = (const float*)d_in[10];
    const float* w_hh     = (const float*)d_in[11];
    const float* b_ih     = (const float*)d_in[12];
    const float* b_hh     = (const float*)d_in[13];
    const float* fc_w     = (const float*)d_in[14];
    const float* fc_b     = (const float*)d_in[15];
    float* out = (float*)d_out;

    // workspace: S[GG] f32 | row_ptr[304] | csr_pos[EE]  (~50 KB)
    char* ws = (char*)d_ws;
    float* S       = (float*)ws;
    int*   row_ptr = (int*)(ws + GG * 4);
    int*   csr_pos = row_ptr + 304;

    build_csr<<<1, 1024, 0, stream>>>(src, dst, row_ptr, csr_pos);
    gat_pool<<<GG, 512, 0, stream>>>(x, ew, src, dst, w_node, w_edge,
                                     attn_l, attn_r, attn_e,
                                     row_ptr, csr_pos, S);
    gru_fc<<<B_, 256, 0, stream>>>(S, w_node, gat_bias, w_ih, w_hh,
                                   b_ih, b_hh, fc_w, fc_b, out);
}